// Round 11
// baseline (220.756 us; speedup 1.0000x reference)
//
#include <hip/hip_runtime.h>

typedef unsigned short ushort_t;
typedef __attribute__((ext_vector_type(8))) short bf16x8;     // 8 bf16 in 4 VGPRs
typedef __attribute__((ext_vector_type(4))) float f32x4;
typedef __attribute__((ext_vector_type(4))) unsigned short u16x4;
typedef __attribute__((ext_vector_type(16))) float f32x16;

__device__ __forceinline__ unsigned short f2bf(float f) {
    union { float f; unsigned u; } v; v.f = f;
    unsigned r = v.u + 0x7FFFu + ((v.u >> 16) & 1u);   // RNE
    return (unsigned short)(r >> 16);
}

// v_cvt_pk_bf16_f32: lo=RNE(a), hi=RNE(b) — bit-identical to f2bf, 1 inst / 2 elems
__device__ __forceinline__ unsigned cvt_pk_bf16(float a, float b) {
    unsigned r;
    asm("v_cvt_pk_bf16_f32 %0, %1, %2" : "=v"(r) : "v"(a), "v"(b));
    return r;
}

// ================= weight prep v14: wave-per-row conv-fold via LDS =================
// Old prep did 426k x 9 gathered L2 loads (latency-chained) + 524k transpose-gathers —
// suspected ~50-70us (the constant 134us total-minus-mega gap). New structure:
//  Part A (blocks 0..127):   one WAVE per fc1 row n. Stage the 676-f32 row into a
//    zero-padded 30x30 LDS image once; each of the row's 832 outputs = 9 LDS reads +
//    9 FMAs. Padding makes taps branch-free; LDS replaces all gathered re-reads.
//  Part B (blocks 128..383): W2 transcode, 4 elems/thread, float4 read + ushort4 write.
//  Part C (block 384):       W3 pad/transcode.
// Layout unchanged: Wf[(ngrp*KFRAGS + kfrag)*512 + (khalf*32 + r32)*8 + e],
// W1eff folds the 3x3 conv into fc1 (p indexes 28x28 input, zero-padded to 832).
__global__ __launch_bounds__(256) void prep_w(const float* __restrict__ fc1_w,
                                              const float* __restrict__ cw,
                                              const float* __restrict__ fc2_w,
                                              const float* __restrict__ out_w,
                                              ushort_t* __restrict__ W1,
                                              ushort_t* __restrict__ W2,
                                              ushort_t* __restrict__ W3) {
    __shared__ float Fp[4][900];                       // 30x30 padded image per wave
    const int tid = threadIdx.x, bid = blockIdx.x;
    if (bid < 128) {
        const int wid = tid >> 6, lane = tid & 63;
        const int n = bid * 4 + wid;                   // this wave's fc1 row
        float* F = Fp[wid];
#pragma unroll
        for (int t = 0; t < 15; ++t) {                 // zero the padded frame
            const int i = t * 64 + lane;
            if (i < 900) F[i] = 0.f;
        }
        __syncthreads();
#pragma unroll
        for (int t = 0; t < 11; ++t) {                 // stage row: F[(r+2)*30 + (c+2)]
            const int i = t * 64 + lane;
            if (i < 676) {
                const int r = i / 26, c = i - r * 26;
                F[(r + 2) * 30 + (c + 2)] = fc1_w[n * 676 + i];
            }
        }
        __syncthreads();
        const float k00 = cw[0], k01 = cw[1], k02 = cw[2];
        const float k10 = cw[3], k11 = cw[4], k12 = cw[5];
        const float k20 = cw[6], k21 = cw[7], k22 = cw[8];
        const int ngrp = n >> 5, r32n = n & 31;
#pragma unroll
        for (int t = 0; t < 13; ++t) {                 // 832 outputs, 64 lanes x 13
            const int p = t * 64 + lane;
            float v = 0.f;
            if (p < 784) {
                const int pr = p / 28, pc = p - pr * 28;
                const int rb = (pr + 2) * 30 + (pc + 2);
                v = k00 * F[rb]      + k01 * F[rb - 1]  + k02 * F[rb - 2]
                  + k10 * F[rb - 30] + k11 * F[rb - 31] + k12 * F[rb - 32]
                  + k20 * F[rb - 60] + k21 * F[rb - 61] + k22 * F[rb - 62];
            }
            W1[(ngrp * 52 + (p >> 4)) * 512 + (((p >> 3) & 1) * 32 + r32n) * 8 + (p & 7)] = f2bf(v);
        }
    } else if (bid < 384) {
        // W2f: 262144 elements, 4/thread; same fragment layout, vectorized transcode
        const int base = (bid - 128) * 1024 + tid * 4;
        const int ngrp = base >> 14;
        const int kfrag = (base >> 9) & 31;
        const int li = base & 511;
        const int lane = li >> 3;
        const int n = ngrp * 32 + (lane & 31);
        const int p0 = kfrag * 16 + (lane >> 5) * 8 + (li & 7);
        const f32x4 v = *(const f32x4*)&fc2_w[n * 512 + p0];
        u16x4 o;
        o[0] = f2bf(v.x); o[1] = f2bf(v.y); o[2] = f2bf(v.z); o[3] = f2bf(v.w);
        *(u16x4*)&W2[base] = o;
    } else {
        for (int idx = tid; idx < 8192; idx += 256)
            W3[idx] = (idx < 5120) ? f2bf(out_w[idx]) : (ushort_t)0;
    }
}

// ================= fully-fused network, v13 (unchanged): v5 + explicit W software pipeline =================
// 512 blocks x 64 batch rows, 512 threads (8 waves), launch_bounds(512,4): 128 regs/wave,
// 2 blocks/CU (72KB LDS), 4 waves/SIMD. Wave w owns 64x64 (n-groups 2w,2w+1):
// acc[2][2] = 64 AGPR. Hand-rotated 1-kfrag-deep W prefetch (bwc/bwn).
__global__ __launch_bounds__(512, 4) void mega13(const float* __restrict__ x,
                                                 const ushort_t* __restrict__ W1,
                                                 const ushort_t* __restrict__ W2,
                                                 const ushort_t* __restrict__ W3,
                                                 const float* __restrict__ b1,
                                                 const float* __restrict__ b2,
                                                 const float* __restrict__ ob,
                                                 float* __restrict__ out) {
    extern __shared__ ushort_t smem[];
    ushort_t* xs0 = smem;                // [64][64]   8 KB  x buffer A (seg-swizzled)
    ushort_t* hs  = smem + 4096;         // [64][512] 64 KB h1/h2 tile; first 8KB = x buffer B

    const int tid = threadIdx.x;
    const int wave = tid >> 6, lane = tid & 63;
    const int r32 = lane & 31, khalf = lane >> 5;
    const int xrow = tid >> 3, xoct = tid & 7;          // x staging: 64 rows x 8 octs
    const int m0 = blockIdx.x * 64;
    const size_t ng0 = wave * 2, ng1 = wave * 2 + 1;    // this wave's two n-groups

    // W fragment base pointers (per-lane, loop-invariant)
    const ushort_t* w1p0 = &W1[ng0 * 52 * 512 + lane * 8];
    const ushort_t* w1p1 = &W1[ng1 * 52 * 512 + lane * 8];
    const ushort_t* w2p0 = &W2[ng0 * 32 * 512 + lane * 8];
    const ushort_t* w2p1 = &W2[ng1 * 32 * 512 + lane * 8];

    f32x16 acc[2][2];                                   // [i = m-frag][j = ngrp]; 64 AGPR
#pragma unroll
    for (int a = 0; a < 2; ++a)
#pragma unroll
        for (int j = 0; j < 2; ++j)
#pragma unroll
            for (int e = 0; e < 16; ++e) acc[a][j][e] = 0.f;

    // ---- x prefetch (nontemporal fp32), one K-step ahead; 1 row-segment / thread ----
    f32x4 xv0, xv1;
    auto load_x = [&](int ks) {
        const int gc = ks * 64 + xoct * 8;
        if (gc < 784) {
            const f32x4* p = (const f32x4*)&x[(size_t)(m0 + xrow) * 784 + gc];
            xv0 = __builtin_nontemporal_load(p);
            xv1 = __builtin_nontemporal_load(p + 1);
        } else {
            xv0 = (f32x4){0.f, 0.f, 0.f, 0.f};
            xv1 = (f32x4){0.f, 0.f, 0.f, 0.f};
        }
    };
    auto store_x = [&](ushort_t* buf) {
        union { bf16x8 h; unsigned u[4]; } a;
        a.u[0] = cvt_pk_bf16(xv0.x, xv0.y); a.u[1] = cvt_pk_bf16(xv0.z, xv0.w);
        a.u[2] = cvt_pk_bf16(xv1.x, xv1.y); a.u[3] = cvt_pk_bf16(xv1.z, xv1.w);
        *(bf16x8*)&buf[xrow * 64 + ((xoct ^ (xrow & 7)) * 8)] = a.h;
    };

    // h-epilogue: bias+relu -> hs (A-layout, seg' = seg ^ (m&7)); cols = this wave's 64 n
    auto write_h = [&](const float* __restrict__ bias) {
#pragma unroll
        for (int j = 0; j < 2; ++j) {
            const int n = (wave * 2 + j) * 32 + r32;
            const float bb = bias[n];
            const int nseg = n >> 3, nrem = n & 7;
#pragma unroll
            for (int i = 0; i < 2; ++i)
#pragma unroll
                for (int reg = 0; reg < 16; ++reg) {
                    const int m = i * 32 + 4 * khalf + (reg & 3) + 8 * (reg >> 2);
                    hs[m * 512 + ((nseg ^ (m & 7)) * 8) + nrem] = f2bf(fmaxf(acc[i][j][reg] + bb, 0.f));
                }
        }
    };

    load_x(0);
    store_x(xs0);
    __syncthreads();

    // ---- W pipeline registers: bwc = current kfrag's fragments, loaded one kfrag early ----
    bf16x8 bwc0 = *(const bf16x8*)(w1p0);               // kfrag 0
    bf16x8 bwc1 = *(const bf16x8*)(w1p1);

    // ---------------- phase 1: K = 832, kfrags 0..48 (49..51 zero pad skipped) ----------------
    for (int ks = 0; ks < 12; ++ks) {
        load_x(ks + 1);                                 // next x flies under the MFMAs
        const ushort_t* bufp = (ks & 1) ? hs : xs0;
#pragma unroll
        for (int ksub = 0; ksub < 4; ++ksub) {
            const int kf = ks * 4 + ksub;
            bf16x8 bwn0, bwn1;
            if (kf < 48) {
                bwn0 = *(const bf16x8*)(w1p0 + (kf + 1) * 512);
                bwn1 = *(const bf16x8*)(w1p1 + (kf + 1) * 512);
            } else {                                    // cross-phase: prefetch W2 kfrag 0
                bwn0 = *(const bf16x8*)(w2p0);
                bwn1 = *(const bf16x8*)(w2p1);
            }
            const int q = 2 * ksub + khalf;
            bf16x8 af[2];
#pragma unroll
            for (int i = 0; i < 2; ++i) {
                const int m = i * 32 + r32;
                af[i] = *(const bf16x8*)&bufp[m * 64 + ((q ^ (m & 7)) * 8)];
            }
            __builtin_amdgcn_s_setprio(1);
            acc[0][0] = __builtin_amdgcn_mfma_f32_32x32x16_bf16(af[0], bwc0, acc[0][0], 0, 0, 0);
            acc[0][1] = __builtin_amdgcn_mfma_f32_32x32x16_bf16(af[0], bwc1, acc[0][1], 0, 0, 0);
            acc[1][0] = __builtin_amdgcn_mfma_f32_32x32x16_bf16(af[1], bwc0, acc[1][0], 0, 0, 0);
            acc[1][1] = __builtin_amdgcn_mfma_f32_32x32x16_bf16(af[1], bwc1, acc[1][1], 0, 0, 0);
            __builtin_amdgcn_s_setprio(0);
            bwc0 = bwn0; bwc1 = bwn1;
        }
        store_x((ks & 1) ? xs0 : hs);                   // fill the other buffer
        __syncthreads();
    }
    // ---- kfrag 48 (cols 768..783 real; 784..831 zero pad skipped) ----
    {
        const ushort_t* bufp = xs0;                     // ks=12 even -> buffer A
        bf16x8 bwn0 = *(const bf16x8*)(w2p0);           // prefetch phase-2 kfrag 0
        bf16x8 bwn1 = *(const bf16x8*)(w2p1);
        const int q = khalf;
        bf16x8 af[2];
#pragma unroll
        for (int i = 0; i < 2; ++i) {
            const int m = i * 32 + r32;
            af[i] = *(const bf16x8*)&bufp[m * 64 + ((q ^ (m & 7)) * 8)];
        }
        __builtin_amdgcn_s_setprio(1);
        acc[0][0] = __builtin_amdgcn_mfma_f32_32x32x16_bf16(af[0], bwc0, acc[0][0], 0, 0, 0);
        acc[0][1] = __builtin_amdgcn_mfma_f32_32x32x16_bf16(af[0], bwc1, acc[0][1], 0, 0, 0);
        acc[1][0] = __builtin_amdgcn_mfma_f32_32x32x16_bf16(af[1], bwc0, acc[1][0], 0, 0, 0);
        acc[1][1] = __builtin_amdgcn_mfma_f32_32x32x16_bf16(af[1], bwc1, acc[1][1], 0, 0, 0);
        __builtin_amdgcn_s_setprio(0);
        bwc0 = bwn0; bwc1 = bwn1;                       // now holds W2 kfrag 0
    }

    // ---- h1 = relu(acc + b1) -> hs ----
    write_h(b1);
#pragma unroll
    for (int a = 0; a < 2; ++a)
#pragma unroll
        for (int j = 0; j < 2; ++j)
#pragma unroll
            for (int e = 0; e < 16; ++e) acc[a][j][e] = 0.f;
    __syncthreads();

    // ---------------- phase 2: K = 512, kfrags 0..31, no barriers, same pipeline ----------------
    for (int ks = 0; ks < 8; ++ks) {
#pragma unroll
        for (int ksub = 0; ksub < 4; ++ksub) {
            const int kf = ks * 4 + ksub;
            bf16x8 bwn0, bwn1;
            if (kf < 31) {
                bwn0 = *(const bf16x8*)(w2p0 + (kf + 1) * 512);
                bwn1 = *(const bf16x8*)(w2p1 + (kf + 1) * 512);
            }
            const int hq = kf * 2 + khalf;              // 16B-seg index within hs row (0..63)
            bf16x8 af[2];
#pragma unroll
            for (int i = 0; i < 2; ++i) {
                const int m = i * 32 + r32;
                af[i] = *(const bf16x8*)&hs[m * 512 + ((hq ^ (m & 7)) * 8)];
            }
            __builtin_amdgcn_s_setprio(1);
            acc[0][0] = __builtin_amdgcn_mfma_f32_32x32x16_bf16(af[0], bwc0, acc[0][0], 0, 0, 0);
            acc[0][1] = __builtin_amdgcn_mfma_f32_32x32x16_bf16(af[0], bwc1, acc[0][1], 0, 0, 0);
            acc[1][0] = __builtin_amdgcn_mfma_f32_32x32x16_bf16(af[1], bwc0, acc[1][0], 0, 0, 0);
            acc[1][1] = __builtin_amdgcn_mfma_f32_32x32x16_bf16(af[1], bwc1, acc[1][1], 0, 0, 0);
            __builtin_amdgcn_s_setprio(0);
            if (kf < 31) { bwc0 = bwn0; bwc1 = bwn1; }
        }
    }
    __syncthreads();                                    // all hs(h1) reads done

    // ---- h2 = relu(acc + b2) -> hs ----
    write_h(b2);
    __syncthreads();

    // ---------------- head: waves 0..3 -> 16 rows each, K=512, direct stores ----------------
    if (wave < 4) {
        const int quad = lane >> 4, l16 = lane & 15;
        const int row = wave * 16 + l16;
        f32x4 hacc = {0.f, 0.f, 0.f, 0.f};
#pragma unroll
        for (int ks = 0; ks < 16; ++ks) {
            const int seg = 4 * ks + quad;
            const bf16x8 a = *(const bf16x8*)&hs[row * 512 + ((seg ^ (row & 7)) * 8)];
            const bf16x8 b = *(const bf16x8*)&W3[l16 * 512 + ks * 32 + quad * 8];
            hacc = __builtin_amdgcn_mfma_f32_16x16x32_bf16(a, b, hacc, 0, 0, 0);
        }
        if (l16 < 10) {
            const float bb = ob[l16];
#pragma unroll
            for (int r = 0; r < 4; ++r)
                out[(size_t)(m0 + wave * 16 + quad * 4 + r) * 10 + l16] = hacc[r] + bb;
        }
    }
}

extern "C" void kernel_launch(void* const* d_in, const int* in_sizes, int n_in,
                              void* d_out, int out_size, void* d_ws, size_t ws_size,
                              hipStream_t stream) {
    const float* x      = (const float*)d_in[0];
    const float* conv_w = (const float*)d_in[1];
    const float* fc1_w  = (const float*)d_in[2];
    const float* fc1_b  = (const float*)d_in[3];
    const float* fc2_w  = (const float*)d_in[4];
    const float* fc2_b  = (const float*)d_in[5];
    const float* out_w  = (const float*)d_in[6];
    const float* out_b  = (const float*)d_in[7];
    float* out = (float*)d_out;

    // workspace: W1f | W2f | W3 (≈1.4 MB total), fragment-major layouts
    ushort_t* W1 = (ushort_t*)d_ws;                    // 16*52*512
    ushort_t* W2 = W1 + 425984;                        // 16*32*512
    ushort_t* W3 = W2 + 262144;                        // 16*512

    // v14 prep: 128 conv-fold blocks (wave-per-row) + 256 W2 blocks + 1 W3 block
    prep_w<<<dim3(385), 256, 0, stream>>>(fc1_w, conv_w, fc2_w, out_w, W1, W2, W3);

    // 512 blocks x 64 rows; 512 threads (8 waves); 72 KB dynamic LDS;
    // launch_bounds(512,4): 128 regs/wave, 2 blocks/CU, explicit W software pipeline
    mega13<<<dim3(512), 512, 73728, stream>>>(x, W1, W2, W3, fc1_b, fc2_b, out_b, out);
}